// Round 7
// baseline (350.834 us; speedup 1.0000x reference)
//
#include <hip/hip_runtime.h>

#define NQ 14
#define NL 6
#define DIM (1 << NQ)   // 16384 amplitudes
#define TPB 1024

// ---------------------------------------------------------------------------
// One block (1024 thr = 16 waves = 4 waves/SIMD) per sample; state in 128 KiB
// dynamic LDS (swizzled). 16 amps/thread => r[16] = 32 VGPRs live state:
// fits the 128-VGPR budget the allocator insists on (rounds 3-5: occupancy
// hints ignored, 128-VGPR budget, r[32] spilled ~400 MB/dispatch to scratch).
//
// Layer 0 is a product state (RX+Rot single-qubit): computed in registers and
// written through the layer-0 entangler permutation (no init, no RMW).
// Layers 1..5: 4 fused passes (4+4+4+2 gate bits); each layer's CNOT
// entangler is a GF(2)-linear index permutation folded into the last pass's
// writeback via compile-time tables (structure verified exact, absmax 0.0).
// ---------------------------------------------------------------------------
struct Tbl {
    unsigned short Wt[NL][TPB];
    unsigned short Wk[NL][16];
};

constexpr Tbl buildTbl() {
    Tbl T{};
    for (int l = 0; l < NL; ++l) {
        const int rng = l + 1;   // entangler range r = (l % (NQ-1)) + 1
        unsigned short col[NQ] = {};
        for (int p = 0; p < NQ; ++p) col[p] = (unsigned short)(1 << p);
        for (int w = 0; w < NQ; ++w) {
            int c = NQ - 1 - w;
            int g = NQ - 1 - ((w + rng) % NQ);
            col[c] ^= col[g];
        }
        unsigned int M[NQ] = {}, Inv[NQ] = {};
        for (int q = 0; q < NQ; ++q) {
            M[q] = 0;
            for (int p = 0; p < NQ; ++p) M[q] |= (unsigned)((col[p] >> q) & 1) << p;
            Inv[q] = 1u << q;
        }
        for (int cp = 0; cp < NQ; ++cp) {
            int piv = cp;
            while (!((M[piv] >> cp) & 1)) ++piv;
            unsigned tmp = M[piv]; M[piv] = M[cp]; M[cp] = tmp;
            tmp = Inv[piv]; Inv[piv] = Inv[cp]; Inv[cp] = tmp;
            for (int q = 0; q < NQ; ++q)
                if (q != cp && ((M[q] >> cp) & 1)) { M[q] ^= M[cp]; Inv[q] ^= Inv[cp]; }
        }
        unsigned short colInv[NQ] = {};
        for (int p = 0; p < NQ; ++p) {
            unsigned short v = 0;
            for (int q = 0; q < NQ; ++q) v |= (unsigned short)(((Inv[q] >> p) & 1) << q);
            colInv[p] = v;
        }
        // pass-3 coset shape (TPB=1024, 16 amps):
        //   t bits 0..9 -> h bits 2..11; k bits 2,3 -> h bits 0,1;
        //   k bits 0,1 -> h bits 12,13
        for (int t = 0; t < TPB; ++t) {
            int ht = t << 2;
            int r2 = 0;
            for (int p = 0; p < NQ; ++p) if ((ht >> p) & 1) r2 ^= colInv[p];
            T.Wt[l][t] = (unsigned short)(r2 ^ ((r2 >> 6) & 63));
        }
        for (int k = 0; k < 16; ++k) {
            int hk = ((k >> 2) & 3) | ((k & 3) << 12);
            int r2 = 0;
            for (int p = 0; p < NQ; ++p) if ((hk >> p) & 1) r2 ^= colInv[p];
            T.Wk[l][k] = (unsigned short)(r2 ^ ((r2 >> 6) & 63));
        }
    }
    return T;
}

__device__ const Tbl dT = buildTbl();

__device__ __forceinline__ int swz(int h) { return h ^ ((h >> 6) & 63); }

__device__ __forceinline__ float2 cmul(float2 a, float2 b) {
    return make_float2(a.x * b.x - a.y * b.y, a.x * b.y + a.y * b.x);
}

template <int S>
__device__ __forceinline__ int haddr(int t, int k) {
    int h;
    if constexpr (S == 0) {
        h = (t << 4) | k;                                        // k -> h bits 0..3
    } else if constexpr (S == 1) {
        h = (t & 15) | (k << 4) | ((t >> 4) << 8);               // k -> h bits 4..7
    } else if constexpr (S == 2) {
        h = (t & 255) | (k << 8) | ((t >> 8) << 12);             // k -> h bits 8..11
    } else {
        h = (t << 2) | ((k >> 2) & 3) | ((k & 3) << 12);         // k -> h {12,13,0,1}
    }
    return swz(h);
}

__device__ __forceinline__ void gate2(float2 u0, float2 u1, float2 u2, float2 u3,
                                      float2& A, float2& C) {
    float2 a = A, c = C, na, nc;
    na.x = u0.x * a.x - u0.y * a.y + u1.x * c.x - u1.y * c.y;
    na.y = u0.x * a.y + u0.y * a.x + u1.x * c.y + u1.y * c.x;
    nc.x = u2.x * a.x - u2.y * a.y + u3.x * c.x - u3.y * c.y;
    nc.y = u2.x * a.y + u2.y * a.x + u3.x * c.y + u3.y * c.x;
    A = na; C = nc;
}

template <int S>
__device__ __forceinline__ void doPass(float2* st, const float2 (*U)[4], int l, int t,
                                       const unsigned short* wt, const unsigned short* wk) {
    float2 r[16];
#pragma unroll
    for (int k = 0; k < 16; ++k) r[k] = st[haddr<S>(t, k)];

    if constexpr (S == 3) __syncthreads();   // all reads done before permuted writes

    constexpr int NG = (S == 3) ? 2 : 4;
#pragma unroll
    for (int j = 0; j < NG; ++j) {
        // pass S gates: S0 -> wires 13..10, S1 -> 9..6, S2 -> 5..2, S3 -> 1,0
        const int w = (S == 0) ? (13 - j) : (S == 1) ? (9 - j)
                    : (S == 2) ? (5 - j) : (1 - j);
        const float2* u = U[l * NQ + w];
        float2 u0 = u[0], u1 = u[1], u2 = u[2], u3 = u[3];
#pragma unroll
        for (int m = 0; m < 8; ++m) {
            const int k0 = ((m >> j) << (j + 1)) | (m & ((1 << j) - 1));
            gate2(u0, u1, u2, u3, r[k0], r[k0 | (1 << j)]);
        }
    }

    if constexpr (S == 3) {
        const int at = wt[t];
#pragma unroll
        for (int k = 0; k < 16; ++k) st[at ^ wk[k]] = r[k];
    } else {
#pragma unroll
        for (int k = 0; k < 16; ++k) st[haddr<S>(t, k)] = r[k];
    }
}

__global__ __launch_bounds__(TPB) __attribute__((amdgpu_waves_per_eu(4, 4)))
void qc_kernel(const float* __restrict__ x,
               const float* __restrict__ wts,
               const float* __restrict__ fcw,
               const float* __restrict__ fcb,
               float* __restrict__ out)
{
    extern __shared__ float2 st[];           // DIM float2 = 128 KiB (swizzled layout)
    __shared__ float2 U[NL * NQ][4];         // Rot (layer0: Rot*RX) matrices
    __shared__ float2 R[NQ][4];              // RX matrices (temp)
    __shared__ float wsum[TPB / 64];

    const int b = blockIdx.x;
    const int t = threadIdx.x;

    // gate matrices
    if (t < NQ) {
        float th = 0.5f * x[b * NQ + t];
        float c = cosf(th), s = sinf(th);
        R[t][0] = make_float2(c, 0.f);
        R[t][1] = make_float2(0.f, -s);
        R[t][2] = make_float2(0.f, -s);
        R[t][3] = make_float2(c, 0.f);
    }
    if (t >= 64 && t < 64 + NL * NQ) {
        int g = t - 64;
        float phi = wts[g * 3 + 0];
        float th  = wts[g * 3 + 1];
        float om  = wts[g * 3 + 2];
        float c = cosf(0.5f * th), s = sinf(0.5f * th);
        float aa = 0.5f * (phi + om), dd = 0.5f * (phi - om);
        float ca = cosf(aa), sa = sinf(aa);
        float cd = cosf(dd), sd = sinf(dd);
        U[g][0] = make_float2( ca * c, -sa * c);
        U[g][1] = make_float2(-cd * s, -sd * s);
        U[g][2] = make_float2( cd * s, -sd * s);
        U[g][3] = make_float2( ca * c,  sa * c);
    }
    __syncthreads();

    // fold RX into layer-0 Rot: U0 = Rot * RX
    if (t < NQ) {
        float2 a00 = U[t][0], a01 = U[t][1], a10 = U[t][2], a11 = U[t][3];
        float2 b00 = R[t][0], b01 = R[t][1], b10 = R[t][2], b11 = R[t][3];
        auto ca2 = [](float2 p, float2 q) { return make_float2(p.x + q.x, p.y + q.y); };
        U[t][0] = ca2(cmul(a00, b00), cmul(a01, b10));
        U[t][1] = ca2(cmul(a00, b01), cmul(a01, b11));
        U[t][2] = ca2(cmul(a10, b00), cmul(a11, b10));
        U[t][3] = ca2(cmul(a10, b01), cmul(a11, b11));
    }
    __syncthreads();

    // ---- layer 0: product state (Rot*RX)|0> written through entangler-0 ----
    // amp(h) = prod_p cv[p][h_p]; wire of h bit p is 13-p; cv = col 0 of U.
    // pass-3 shape: h = (t<<2) | ((k>>2)&3) | ((k&3)<<12)
    {
        float2 A = make_float2(1.f, 0.f);
#pragma unroll
        for (int i = 0; i < 10; ++i) {           // h bit 2+i = t bit i, wire 11-i
            float2 v0 = U[11 - i][0], v1 = U[11 - i][2];
            A = cmul(A, ((t >> i) & 1) ? v1 : v0);
        }
        float2 AP[4], P[4];
#pragma unroll
        for (int g = 0; g < 4; ++g) {
            float2 w12v = (g & 1) ? U[1][2] : U[1][0];   // h bit 12 = k0, wire 1
            float2 w13v = (g & 2) ? U[0][2] : U[0][0];   // h bit 13 = k1, wire 0
            AP[g] = cmul(A, cmul(w12v, w13v));
            float2 h0v = (g & 1) ? U[13][2] : U[13][0];  // h bit 0 = k2, wire 13
            float2 h1v = (g & 2) ? U[12][2] : U[12][0];  // h bit 1 = k3, wire 12
            P[g] = cmul(h0v, h1v);
        }
        const int at = dT.Wt[0][t];
#pragma unroll
        for (int k = 0; k < 16; ++k)
            st[at ^ dT.Wk[0][k]] = cmul(AP[k & 3], P[k >> 2]);
    }
    __syncthreads();

    // ---- layers 1..5: 4 fused passes; entangler folded into pass-3 write ----
    for (int l = 1; l < NL; ++l) {
        doPass<0>(st, U, l, t, nullptr, nullptr);
        __syncthreads();
        doPass<1>(st, U, l, t, nullptr, nullptr);
        __syncthreads();
        doPass<2>(st, U, l, t, nullptr, nullptr);
        __syncthreads();
        doPass<3>(st, U, l, t, dT.Wt[l], dT.Wk[l]);
        __syncthreads();
    }

    // ---- fused expectation + FC (storage identity-mapped, swizzled) ----
    // pass-0 shape: h bits 0..3 = k (wires 13-j), h bits 4..13 = t (wire 9-i)
    float fw[NQ];
#pragma unroll
    for (int w = 0; w < NQ; ++w) fw[w] = fcw[w];

    float gl = 0.f;
#pragma unroll
    for (int i = 0; i < 10; ++i) gl += ((t >> i) & 1) ? -fw[9 - i] : fw[9 - i];

    float acc = 0.f;
#pragma unroll
    for (int k = 0; k < 16; ++k) {
        float2 a = st[haddr<0>(t, k)];
        float p = a.x * a.x + a.y * a.y;
        float g = gl;
#pragma unroll
        for (int j = 0; j < 4; ++j)
            g += ((k >> j) & 1) ? -fw[13 - j] : fw[13 - j];
        acc = fmaf(p, g, acc);
    }

#pragma unroll
    for (int off = 32; off > 0; off >>= 1) acc += __shfl_down(acc, off, 64);
    if ((t & 63) == 0) wsum[t >> 6] = acc;
    __syncthreads();
    if (t == 0) {
        float s = 0.f;
#pragma unroll
        for (int wv = 0; wv < TPB / 64; ++wv) s += wsum[wv];
        out[b] = s + fcb[0];
    }
}

extern "C" void kernel_launch(void* const* d_in, const int* in_sizes, int n_in,
                              void* d_out, int out_size, void* d_ws, size_t ws_size,
                              hipStream_t stream)
{
    const float* x   = (const float*)d_in[0];   // (512, 14)
    const float* wts = (const float*)d_in[1];   // (6, 14, 3)
    const float* fcw = (const float*)d_in[2];   // (1, 14)
    const float* fcb = (const float*)d_in[3];   // (1,)
    float* out = (float*)d_out;                 // (512,)

    const int batch = in_sizes[0] / NQ;         // 512
    const size_t lds_bytes = (size_t)DIM * sizeof(float2);  // 131072

    static bool attr_set = false;
    if (!attr_set) {
        (void)hipFuncSetAttribute((const void*)qc_kernel,
                                  hipFuncAttributeMaxDynamicSharedMemorySize,
                                  (int)lds_bytes);
        attr_set = true;
    }

    qc_kernel<<<batch, TPB, lds_bytes, stream>>>(x, wts, fcw, fcb, out);
}

// Round 8
// 331.651 us; speedup vs baseline: 1.0578x; 1.0578x over previous
//
#include <hip/hip_runtime.h>

#define NQ 14
#define NL 6
#define DIM (1 << NQ)   // 16384 amplitudes
#define TPB 1024

// ---------------------------------------------------------------------------
// One block (1024 thr = 16 waves = 4 waves/SIMD) per sample; state in 128 KiB
// STATIC LDS (swizzled). Static (not dynamic) is load-bearing: the register
// allocator derives its occupancy target from visible resources; with dynamic
// LDS it saw 3.5 KB, targeted 2 workgroups/CU, capped VGPRs at 64 and spilled
// r[16] (~500 MB/dispatch scratch traffic, rounds 3-7). With 134 KiB static
// LDS it must target 1 WG/CU -> 4 waves/EU -> 128-VGPR budget -> no spill.
//
// Layer 0 is a product state (RX+Rot single-qubit): computed in registers and
// written through the layer-0 entangler permutation (no init, no RMW).
// Layers 1..5: 4 fused passes (4+4+4+2 gate bits); each layer's CNOT
// entangler is a GF(2)-linear index permutation folded into the last pass's
// writeback via compile-time tables (verified exact, absmax 0.0).
// ---------------------------------------------------------------------------
struct Tbl {
    unsigned short Wt[NL][TPB];
    unsigned short Wk[NL][16];
};

constexpr Tbl buildTbl() {
    Tbl T{};
    for (int l = 0; l < NL; ++l) {
        const int rng = l + 1;   // entangler range r = (l % (NQ-1)) + 1
        unsigned short col[NQ] = {};
        for (int p = 0; p < NQ; ++p) col[p] = (unsigned short)(1 << p);
        for (int w = 0; w < NQ; ++w) {
            int c = NQ - 1 - w;
            int g = NQ - 1 - ((w + rng) % NQ);
            col[c] ^= col[g];
        }
        unsigned int M[NQ] = {}, Inv[NQ] = {};
        for (int q = 0; q < NQ; ++q) {
            M[q] = 0;
            for (int p = 0; p < NQ; ++p) M[q] |= (unsigned)((col[p] >> q) & 1) << p;
            Inv[q] = 1u << q;
        }
        for (int cp = 0; cp < NQ; ++cp) {
            int piv = cp;
            while (!((M[piv] >> cp) & 1)) ++piv;
            unsigned tmp = M[piv]; M[piv] = M[cp]; M[cp] = tmp;
            tmp = Inv[piv]; Inv[piv] = Inv[cp]; Inv[cp] = tmp;
            for (int q = 0; q < NQ; ++q)
                if (q != cp && ((M[q] >> cp) & 1)) { M[q] ^= M[cp]; Inv[q] ^= Inv[cp]; }
        }
        unsigned short colInv[NQ] = {};
        for (int p = 0; p < NQ; ++p) {
            unsigned short v = 0;
            for (int q = 0; q < NQ; ++q) v |= (unsigned short)(((Inv[q] >> p) & 1) << q);
            colInv[p] = v;
        }
        // pass-3 coset shape (TPB=1024, 16 amps):
        //   t bits 0..9 -> h bits 2..11; k bits 2,3 -> h bits 0,1;
        //   k bits 0,1 -> h bits 12,13
        for (int t = 0; t < TPB; ++t) {
            int ht = t << 2;
            int r2 = 0;
            for (int p = 0; p < NQ; ++p) if ((ht >> p) & 1) r2 ^= colInv[p];
            T.Wt[l][t] = (unsigned short)(r2 ^ ((r2 >> 6) & 63));
        }
        for (int k = 0; k < 16; ++k) {
            int hk = ((k >> 2) & 3) | ((k & 3) << 12);
            int r2 = 0;
            for (int p = 0; p < NQ; ++p) if ((hk >> p) & 1) r2 ^= colInv[p];
            T.Wk[l][k] = (unsigned short)(r2 ^ ((r2 >> 6) & 63));
        }
    }
    return T;
}

__device__ const Tbl dT = buildTbl();

__device__ __forceinline__ int swz(int h) { return h ^ ((h >> 6) & 63); }

__device__ __forceinline__ float2 cmul(float2 a, float2 b) {
    return make_float2(a.x * b.x - a.y * b.y, a.x * b.y + a.y * b.x);
}

template <int S>
__device__ __forceinline__ int haddr(int t, int k) {
    int h;
    if constexpr (S == 0) {
        h = (t << 4) | k;                                        // k -> h bits 0..3
    } else if constexpr (S == 1) {
        h = (t & 15) | (k << 4) | ((t >> 4) << 8);               // k -> h bits 4..7
    } else if constexpr (S == 2) {
        h = (t & 255) | (k << 8) | ((t >> 8) << 12);             // k -> h bits 8..11
    } else {
        h = (t << 2) | ((k >> 2) & 3) | ((k & 3) << 12);         // k -> h {12,13,0,1}
    }
    return swz(h);
}

__device__ __forceinline__ void gate2(float2 u0, float2 u1, float2 u2, float2 u3,
                                      float2& A, float2& C) {
    float2 a = A, c = C, na, nc;
    na.x = u0.x * a.x - u0.y * a.y + u1.x * c.x - u1.y * c.y;
    na.y = u0.x * a.y + u0.y * a.x + u1.x * c.y + u1.y * c.x;
    nc.x = u2.x * a.x - u2.y * a.y + u3.x * c.x - u3.y * c.y;
    nc.y = u2.x * a.y + u2.y * a.x + u3.x * c.y + u3.y * c.x;
    A = na; C = nc;
}

template <int S>
__device__ __forceinline__ void doPass(float2* st, const float2 (*U)[4], int l, int t,
                                       const unsigned short* wt, const unsigned short* wk) {
    float2 r[16];
#pragma unroll
    for (int k = 0; k < 16; ++k) r[k] = st[haddr<S>(t, k)];

    if constexpr (S == 3) __syncthreads();   // all reads done before permuted writes

    constexpr int NG = (S == 3) ? 2 : 4;
#pragma unroll
    for (int j = 0; j < NG; ++j) {
        // pass S gates: S0 -> wires 13..10, S1 -> 9..6, S2 -> 5..2, S3 -> 1,0
        const int w = (S == 0) ? (13 - j) : (S == 1) ? (9 - j)
                    : (S == 2) ? (5 - j) : (1 - j);
        const float2* u = U[l * NQ + w];
        float2 u0 = u[0], u1 = u[1], u2 = u[2], u3 = u[3];
#pragma unroll
        for (int m = 0; m < 8; ++m) {
            const int k0 = ((m >> j) << (j + 1)) | (m & ((1 << j) - 1));
            gate2(u0, u1, u2, u3, r[k0], r[k0 | (1 << j)]);
        }
    }

    if constexpr (S == 3) {
        const int at = wt[t];
#pragma unroll
        for (int k = 0; k < 16; ++k) st[at ^ wk[k]] = r[k];
    } else {
#pragma unroll
        for (int k = 0; k < 16; ++k) st[haddr<S>(t, k)] = r[k];
    }
}

__global__ __launch_bounds__(TPB) __attribute__((amdgpu_waves_per_eu(4, 4)))
void qc_kernel(const float* __restrict__ x,
               const float* __restrict__ wts,
               const float* __restrict__ fcw,
               const float* __restrict__ fcb,
               float* __restrict__ out)
{
    __shared__ float2 st[DIM];               // 128 KiB STATIC LDS (swizzled layout)
    __shared__ float2 U[NL * NQ][4];         // Rot (layer0: Rot*RX) matrices
    __shared__ float2 R[NQ][4];              // RX matrices (temp)
    __shared__ float wsum[TPB / 64];

    const int b = blockIdx.x;
    const int t = threadIdx.x;

    // gate matrices
    if (t < NQ) {
        float th = 0.5f * x[b * NQ + t];
        float c = cosf(th), s = sinf(th);
        R[t][0] = make_float2(c, 0.f);
        R[t][1] = make_float2(0.f, -s);
        R[t][2] = make_float2(0.f, -s);
        R[t][3] = make_float2(c, 0.f);
    }
    if (t >= 64 && t < 64 + NL * NQ) {
        int g = t - 64;
        float phi = wts[g * 3 + 0];
        float th  = wts[g * 3 + 1];
        float om  = wts[g * 3 + 2];
        float c = cosf(0.5f * th), s = sinf(0.5f * th);
        float aa = 0.5f * (phi + om), dd = 0.5f * (phi - om);
        float ca = cosf(aa), sa = sinf(aa);
        float cd = cosf(dd), sd = sinf(dd);
        U[g][0] = make_float2( ca * c, -sa * c);
        U[g][1] = make_float2(-cd * s, -sd * s);
        U[g][2] = make_float2( cd * s, -sd * s);
        U[g][3] = make_float2( ca * c,  sa * c);
    }
    __syncthreads();

    // fold RX into layer-0 Rot: U0 = Rot * RX
    if (t < NQ) {
        float2 a00 = U[t][0], a01 = U[t][1], a10 = U[t][2], a11 = U[t][3];
        float2 b00 = R[t][0], b01 = R[t][1], b10 = R[t][2], b11 = R[t][3];
        auto ca2 = [](float2 p, float2 q) { return make_float2(p.x + q.x, p.y + q.y); };
        U[t][0] = ca2(cmul(a00, b00), cmul(a01, b10));
        U[t][1] = ca2(cmul(a00, b01), cmul(a01, b11));
        U[t][2] = ca2(cmul(a10, b00), cmul(a11, b10));
        U[t][3] = ca2(cmul(a10, b01), cmul(a11, b11));
    }
    __syncthreads();

    // ---- layer 0: product state (Rot*RX)|0> written through entangler-0 ----
    // amp(h) = prod_p cv[p][h_p]; wire of h bit p is 13-p; cv = col 0 of U.
    // pass-3 shape: h = (t<<2) | ((k>>2)&3) | ((k&3)<<12)
    {
        float2 A = make_float2(1.f, 0.f);
#pragma unroll
        for (int i = 0; i < 10; ++i) {           // h bit 2+i = t bit i, wire 11-i
            float2 v0 = U[11 - i][0], v1 = U[11 - i][2];
            A = cmul(A, ((t >> i) & 1) ? v1 : v0);
        }
        float2 AP[4], P[4];
#pragma unroll
        for (int g = 0; g < 4; ++g) {
            float2 w12v = (g & 1) ? U[1][2] : U[1][0];   // h bit 12 = k0, wire 1
            float2 w13v = (g & 2) ? U[0][2] : U[0][0];   // h bit 13 = k1, wire 0
            AP[g] = cmul(A, cmul(w12v, w13v));
            float2 h0v = (g & 1) ? U[13][2] : U[13][0];  // h bit 0 = k2, wire 13
            float2 h1v = (g & 2) ? U[12][2] : U[12][0];  // h bit 1 = k3, wire 12
            P[g] = cmul(h0v, h1v);
        }
        const int at = dT.Wt[0][t];
#pragma unroll
        for (int k = 0; k < 16; ++k)
            st[at ^ dT.Wk[0][k]] = cmul(AP[k & 3], P[k >> 2]);
    }
    __syncthreads();

    // ---- layers 1..5: 4 fused passes; entangler folded into pass-3 write ----
    for (int l = 1; l < NL; ++l) {
        doPass<0>(st, U, l, t, nullptr, nullptr);
        __syncthreads();
        doPass<1>(st, U, l, t, nullptr, nullptr);
        __syncthreads();
        doPass<2>(st, U, l, t, nullptr, nullptr);
        __syncthreads();
        doPass<3>(st, U, l, t, dT.Wt[l], dT.Wk[l]);
        __syncthreads();
    }

    // ---- fused expectation + FC (storage identity-mapped, swizzled) ----
    // pass-0 shape: h bits 0..3 = k (wires 13-j), h bits 4..13 = t (wire 9-i)
    float fw[NQ];
#pragma unroll
    for (int w = 0; w < NQ; ++w) fw[w] = fcw[w];

    float gl = 0.f;
#pragma unroll
    for (int i = 0; i < 10; ++i) gl += ((t >> i) & 1) ? -fw[9 - i] : fw[9 - i];

    float acc = 0.f;
#pragma unroll
    for (int k = 0; k < 16; ++k) {
        float2 a = st[haddr<0>(t, k)];
        float p = a.x * a.x + a.y * a.y;
        float g = gl;
#pragma unroll
        for (int j = 0; j < 4; ++j)
            g += ((k >> j) & 1) ? -fw[13 - j] : fw[13 - j];
        acc = fmaf(p, g, acc);
    }

#pragma unroll
    for (int off = 32; off > 0; off >>= 1) acc += __shfl_down(acc, off, 64);
    if ((t & 63) == 0) wsum[t >> 6] = acc;
    __syncthreads();
    if (t == 0) {
        float s = 0.f;
#pragma unroll
        for (int wv = 0; wv < TPB / 64; ++wv) s += wsum[wv];
        out[b] = s + fcb[0];
    }
}

extern "C" void kernel_launch(void* const* d_in, const int* in_sizes, int n_in,
                              void* d_out, int out_size, void* d_ws, size_t ws_size,
                              hipStream_t stream)
{
    const float* x   = (const float*)d_in[0];   // (512, 14)
    const float* wts = (const float*)d_in[1];   // (6, 14, 3)
    const float* fcw = (const float*)d_in[2];   // (1, 14)
    const float* fcb = (const float*)d_in[3];   // (1,)
    float* out = (float*)d_out;                 // (512,)

    const int batch = in_sizes[0] / NQ;         // 512

    qc_kernel<<<batch, TPB, 0, stream>>>(x, wts, fcw, fcb, out);
}